// Round 13
// baseline (3264.100 us; speedup 1.0000x reference)
//
#include <hip/hip_runtime.h>

// ---------------------------------------------------------------------------
// ROUND 13: mfma_gemm staging via global_load_lds width=16 (m97 ladder rung),
// unpadded [128][64] LDS tiles. Attention/LN/head unchanged from r12.
// fp32 residual/output. B=128 T=256 E=384 H=6 HS=64 L=6 V=78 FF=1536.
// ---------------------------------------------------------------------------

#define Bc 128
#define Tc 256
#define Ec 384
#define Hc 6
#define HSc 64
#define Lc 6
#define Vc 78
#define FFc 1536
#define Mc (Bc * Tc)  // 32768 tokens

typedef unsigned short u16;
using bf16x8 = __attribute__((ext_vector_type(8))) short;
using f32x4 = __attribute__((ext_vector_type(4))) float;

__device__ __forceinline__ float b2f(u16 u) {
    union { float f; unsigned int i; } x;
    x.i = ((unsigned int)u) << 16;
    return x.f;
}
__device__ __forceinline__ u16 f2b(float f) {
    union { float f; unsigned int u; } x;
    x.f = f;
    unsigned int r = x.u + 0x7fffu + ((x.u >> 16) & 1u);  // RNE
    return (u16)(r >> 16);
}

// direct global->LDS 16B copy (CK-pattern casts; LDS dest = wave base+lane*16)
__device__ __forceinline__ void gl_lds16(const void* g, void* l) {
    __builtin_amdgcn_global_load_lds(
        reinterpret_cast<const __attribute__((address_space(1))) unsigned int*>(
            reinterpret_cast<unsigned long long>(g)),
        reinterpret_cast<__attribute__((address_space(3))) unsigned int*>(
            reinterpret_cast<unsigned long long>(l)),
        16, 0, 0);
}

__global__ __launch_bounds__(256) void poison_kernel(
    float* __restrict__ out, int n, float val) {
    int i = blockIdx.x * 256 + threadIdx.x;
    if (i < n) out[i] = val;
}

// --- weight pre-transpose to bf16 [N][K] ------------------------------------
__global__ __launch_bounds__(256) void trans_qkv_kernel(
    const float* __restrict__ in, u16* __restrict__ out) {
    int i = blockIdx.x * 256 + threadIdx.x;  // < L*H*E*192
    if (i >= Lc * Hc * Ec * 192) return;
    int f = i % 192;
    int r = i / 192;
    int e = r % Ec; r /= Ec;
    int h = r % Hc;
    int l = r / Hc;
    out[((size_t)l * 1152 + h * 192 + f) * Ec + e] = f2b(in[i]);
}
__global__ __launch_bounds__(256) void trans_w_kernel(
    const float* __restrict__ in, u16* __restrict__ out, int K, int N) {
    int i = blockIdx.x * 256 + threadIdx.x;  // < L*K*N
    if (i >= Lc * K * N) return;
    int n = i % N;
    int r = i / N;
    int k = r % K;
    int l = r / K;
    out[((size_t)l * N + n) * K + k] = f2b(in[i]);
}
// head: in[e*Vc+v] -> out[v*Ec+e], v<Vc (rows Vc..127 pre-zeroed)
__global__ __launch_bounds__(256) void trans_head_kernel(
    const float* __restrict__ in, u16* __restrict__ out) {
    int i = blockIdx.x * 256 + threadIdx.x;  // < Ec*Vc
    if (i >= Ec * Vc) return;
    int v = i % Vc, e = i / Vc;
    out[(size_t)v * Ec + e] = f2b(in[i]);
}

// --- x[bt,e] = tok_emb[ctx[bt],e] + pos_emb[t,e]  (fp32) --------------------
__global__ __launch_bounds__(256) void embed_kernel(
    const int* __restrict__ ctx, const float* __restrict__ tok,
    const float* __restrict__ pos, float* __restrict__ x) {
    int i = blockIdx.x * 256 + threadIdx.x;
    if (i >= Mc * Ec) return;
    int e = i % Ec, bt = i / Ec, t = bt % Tc;
    x[i] = tok[ctx[bt] * Ec + e] + pos[t * Ec + e];
}

// --- layernorm fp32 in -> bf16 out: one wave per row ------------------------
__global__ __launch_bounds__(256) void ln_kernel(
    const float* __restrict__ X, u16* __restrict__ Y,
    const float* __restrict__ g, const float* __restrict__ b, int nrows) {
    int row = blockIdx.x * 4 + (threadIdx.x >> 6);
    int lane = threadIdx.x & 63;
    if (row >= nrows) return;
    const float* xr = X + (size_t)row * Ec;
    float v[6];
    float s = 0.f;
#pragma unroll
    for (int i = 0; i < 6; ++i) { v[i] = xr[lane + 64 * i]; s += v[i]; }
#pragma unroll
    for (int off = 32; off >= 1; off >>= 1) s += __shfl_xor(s, off, 64);
    float mean = s * (1.0f / Ec);
    float s2 = 0.f;
#pragma unroll
    for (int i = 0; i < 6; ++i) { float d = v[i] - mean; s2 += d * d; }
#pragma unroll
    for (int off = 32; off >= 1; off >>= 1) s2 += __shfl_xor(s2, off, 64);
    float rstd = rsqrtf(s2 * (1.0f / Ec) + 1e-5f);
    u16* yr = Y + (size_t)row * Ec;
#pragma unroll
    for (int i = 0; i < 6; ++i) {
        int e = lane + 64 * i;
        yr[e] = f2b((v[i] - mean) * rstd * g[e] + b[e]);
    }
}

// --- MFMA GEMM: C[*, ldC] = A[M,K](bf16) @ Wt[N,K]^T(bf16) [+bias][+R] ------
// 128x128 tile, BK=64, 4 waves (2x2 of 64x64). Staging via global_load_lds
// width=16 into unpadded [128][64] tiles (m97 layout: dest = 16*tid+4096*j).
// NV = valid N guard (Wt padded to 128-tile in N).
template <bool RELU, bool RESID, bool OUTBF16>
__global__ __launch_bounds__(256) void mfma_gemm(
    const u16* __restrict__ A, const u16* __restrict__ Wt,
    const float* __restrict__ bias, const float* R, void* C,
    int K, int ldC, int NV) {
    __shared__ u16 As[128 * 64];
    __shared__ u16 Bs[128 * 64];
    int tid = threadIdx.x;
    int m0 = blockIdx.y * 128, n0 = blockIdx.x * 128;
    int w = tid >> 6, lane = tid & 63;
    int wm = (w >> 1) * 64, wn = (w & 1) * 64;
    int r16 = lane & 15, quad = lane >> 4;
    int sr = tid >> 3;       // staging row 0..31 (4 passes of 32 rows)
    int sk = (tid & 7) * 8;  // staging k-offset (8 bf16 = 16 B)

    f32x4 acc[4][4] = {};

    for (int k0 = 0; k0 < K; k0 += 64) {
        __syncthreads();
#pragma unroll
        for (int j = 0; j < 4; ++j) {
            int r = sr + 32 * j;
            gl_lds16(&A[(size_t)(m0 + r) * K + k0 + sk], &As[r * 64 + sk]);
            gl_lds16(&Wt[(size_t)(n0 + r) * K + k0 + sk], &Bs[r * 64 + sk]);
        }
        __syncthreads();
#pragma unroll
        for (int kk = 0; kk < 2; ++kk) {
            bf16x8 af[4], bf[4];
#pragma unroll
            for (int i = 0; i < 4; ++i) {
                af[i] = *reinterpret_cast<const bf16x8*>(
                    &As[(wm + i * 16 + r16) * 64 + kk * 32 + quad * 8]);
                bf[i] = *reinterpret_cast<const bf16x8*>(
                    &Bs[(wn + i * 16 + r16) * 64 + kk * 32 + quad * 8]);
            }
#pragma unroll
            for (int mi = 0; mi < 4; ++mi)
#pragma unroll
                for (int ni = 0; ni < 4; ++ni)
                    acc[mi][ni] = __builtin_amdgcn_mfma_f32_16x16x32_bf16(
                        af[mi], bf[ni], acc[mi][ni], 0, 0, 0);
        }
    }

#pragma unroll
    for (int mi = 0; mi < 4; ++mi)
#pragma unroll
        for (int ni = 0; ni < 4; ++ni) {
            int gn = n0 + wn + ni * 16 + r16;
            if (gn >= NV) continue;
            float bv = bias ? bias[gn] : 0.f;
#pragma unroll
            for (int reg = 0; reg < 4; ++reg) {
                int gm = m0 + wm + mi * 16 + quad * 4 + reg;
                float v = acc[mi][ni][reg] + bv;
                if (RESID) v += R[(size_t)gm * ldC + gn];
                if (RELU) v = fmaxf(v, 0.f);
                if (OUTBF16)
                    ((u16*)C)[(size_t)gm * ldC + gn] = f2b(v);
                else
                    ((float*)C)[(size_t)gm * ldC + gn] = v;
            }
        }
}

// --- MFMA flash attention (r11-verified) ------------------------------------
__global__ __launch_bounds__(256) void attn_kernel(
    const u16* __restrict__ qkv, u16* __restrict__ o) {
    __shared__ u16 Qs[64][72];
    __shared__ u16 Ks[64][72];
    __shared__ u16 Vt[64][72];
    __shared__ u16 Ps[4][16][72];
    int tid = threadIdx.x;
    int tt = blockIdx.x, h = blockIdx.y, b = blockIdx.z;
    int w = tid >> 6, lane = tid & 63;
    int r16 = lane & 15, quad = lane >> 4;
    int t0 = tt * 64;
    const u16* base = qkv + (size_t)b * Tc * 1152 + h * 192;

    int sr = tid >> 2, sd = (tid & 3) * 16;
    {
        const u16* src = base + (size_t)(t0 + sr) * 1152 + sd;
        *reinterpret_cast<uint4*>(&Qs[sr][sd]) =
            *reinterpret_cast<const uint4*>(src);
        *reinterpret_cast<uint4*>(&Qs[sr][sd + 8]) =
            *reinterpret_cast<const uint4*>(src + 8);
    }

    float m_run[4], l_run[4];
#pragma unroll
    for (int r = 0; r < 4; ++r) { m_run[r] = -3.0e38f; l_run[r] = 0.f; }
    f32x4 acc_o[4] = {};

    for (int st = 0; st <= tt; ++st) {
        __syncthreads();
        {
            const u16* ks = base + (size_t)(st * 64 + sr) * 1152 + 64 + sd;
            *reinterpret_cast<uint4*>(&Ks[sr][sd]) =
                *reinterpret_cast<const uint4*>(ks);
            *reinterpret_cast<uint4*>(&Ks[sr][sd + 8]) =
                *reinterpret_cast<const uint4*>(ks + 8);
            const u16* vs = base + (size_t)(st * 64 + sr) * 1152 + 128 + sd;
            u16 tv[16];
            *reinterpret_cast<uint4*>(tv) = *reinterpret_cast<const uint4*>(vs);
            *reinterpret_cast<uint4*>(tv + 8) =
                *reinterpret_cast<const uint4*>(vs + 8);
#pragma unroll
            for (int j = 0; j < 16; ++j) Vt[sd + j][sr] = tv[j];
        }
        __syncthreads();

        f32x4 acc_s[4] = {};
        bf16x8 aq0 = *reinterpret_cast<const bf16x8*>(&Qs[w * 16 + r16][quad * 8]);
        bf16x8 aq1 = *reinterpret_cast<const bf16x8*>(&Qs[w * 16 + r16][32 + quad * 8]);
#pragma unroll
        for (int ni = 0; ni < 4; ++ni) {
            bf16x8 bk0 = *reinterpret_cast<const bf16x8*>(&Ks[ni * 16 + r16][quad * 8]);
            bf16x8 bk1 = *reinterpret_cast<const bf16x8*>(&Ks[ni * 16 + r16][32 + quad * 8]);
            acc_s[ni] = __builtin_amdgcn_mfma_f32_16x16x32_bf16(aq0, bk0, acc_s[ni], 0, 0, 0);
            acc_s[ni] = __builtin_amdgcn_mfma_f32_16x16x32_bf16(aq1, bk1, acc_s[ni], 0, 0, 0);
        }

        float sc[4][4];
        float mt[4] = {-3.0e38f, -3.0e38f, -3.0e38f, -3.0e38f};
#pragma unroll
        for (int ni = 0; ni < 4; ++ni)
#pragma unroll
            for (int reg = 0; reg < 4; ++reg) {
                int col = st * 64 + ni * 16 + r16;
                int row = t0 + w * 16 + quad * 4 + reg;
                float v = (col <= row) ? acc_s[ni][reg] * 0.125f : -3.0e38f;
                sc[ni][reg] = v;
                mt[reg] = fmaxf(mt[reg], v);
            }
#pragma unroll
        for (int reg = 0; reg < 4; ++reg) {
#pragma unroll
            for (int off = 1; off <= 8; off <<= 1)
                mt[reg] = fmaxf(mt[reg], __shfl_xor(mt[reg], off, 64));
        }
        float alpha[4], lt[4];
#pragma unroll
        for (int reg = 0; reg < 4; ++reg) {
            float m_new = fmaxf(m_run[reg], mt[reg]);
            alpha[reg] = __expf(m_run[reg] - m_new);
            m_run[reg] = m_new;
            lt[reg] = 0.f;
        }
#pragma unroll
        for (int ni = 0; ni < 4; ++ni)
#pragma unroll
            for (int reg = 0; reg < 4; ++reg) {
                float p = __expf(sc[ni][reg] - m_run[reg]);
                lt[reg] += p;
                Ps[w][quad * 4 + reg][ni * 16 + r16] = f2b(p);
            }
#pragma unroll
        for (int reg = 0; reg < 4; ++reg) {
#pragma unroll
            for (int off = 1; off <= 8; off <<= 1)
                lt[reg] += __shfl_xor(lt[reg], off, 64);
            l_run[reg] = l_run[reg] * alpha[reg] + lt[reg];
        }
#pragma unroll
        for (int ni = 0; ni < 4; ++ni)
#pragma unroll
            for (int reg = 0; reg < 4; ++reg) acc_o[ni][reg] *= alpha[reg];
        __syncthreads();

        bf16x8 ap0 = *reinterpret_cast<const bf16x8*>(&Ps[w][r16][quad * 8]);
        bf16x8 ap1 = *reinterpret_cast<const bf16x8*>(&Ps[w][r16][32 + quad * 8]);
#pragma unroll
        for (int ni = 0; ni < 4; ++ni) {
            bf16x8 bv0 = *reinterpret_cast<const bf16x8*>(&Vt[ni * 16 + r16][quad * 8]);
            bf16x8 bv1 = *reinterpret_cast<const bf16x8*>(&Vt[ni * 16 + r16][32 + quad * 8]);
            acc_o[ni] = __builtin_amdgcn_mfma_f32_16x16x32_bf16(ap0, bv0, acc_o[ni], 0, 0, 0);
            acc_o[ni] = __builtin_amdgcn_mfma_f32_16x16x32_bf16(ap1, bv1, acc_o[ni], 0, 0, 0);
        }
    }

    float inv[4];
#pragma unroll
    for (int reg = 0; reg < 4; ++reg) inv[reg] = 1.0f / l_run[reg];
#pragma unroll
    for (int ni = 0; ni < 4; ++ni)
#pragma unroll
        for (int reg = 0; reg < 4; ++reg) {
            int t = t0 + w * 16 + quad * 4 + reg;
            o[((size_t)b * Tc + t) * Ec + h * 64 + ni * 16 + r16] =
                f2b(acc_o[ni][reg] * inv[reg]);
        }
}

#define GRD(n) dim3(((n) + 255) / 256)

extern "C" void kernel_launch(void* const* d_in, const int* in_sizes, int n_in,
                              void* d_out, int out_size, void* d_ws, size_t ws_size,
                              hipStream_t stream) {
    const int* ctx = (const int*)d_in[0];
    const float* tok = (const float*)d_in[1];
    const float* pos = (const float*)d_in[2];
    const float* ln1g = (const float*)d_in[3];
    const float* ln1b = (const float*)d_in[4];
    const float* wqkv = (const float*)d_in[5];
    const float* wproj = (const float*)d_in[6];
    const float* bproj = (const float*)d_in[7];
    const float* ln2g = (const float*)d_in[8];
    const float* ln2b = (const float*)d_in[9];
    const float* w1 = (const float*)d_in[10];
    const float* b1 = (const float*)d_in[11];
    const float* w2 = (const float*)d_in[12];
    const float* b2 = (const float*)d_in[13];
    const float* lnfg = (const float*)d_in[14];
    const float* lnfb = (const float*)d_in[15];
    const float* whead = (const float*)d_in[16];
    const float* bhead = (const float*)d_in[17];
    float* out = (float*)d_out;

    // ---- workspace layout --------------------------------------------------
    char* ws = (char*)d_ws;
    float* x = (float*)ws;
    size_t off = (size_t)Mc * Ec * 4;                      // 50.3 MB
    u16* wqkvT = (u16*)(ws + off); off += (size_t)Lc * 1152 * 384 * 2;
    u16* wprojT = (u16*)(ws + off); off += (size_t)Lc * 384 * 384 * 2;
    u16* w1T = (u16*)(ws + off); off += (size_t)Lc * 1536 * 384 * 2;
    u16* w2T = (u16*)(ws + off); off += (size_t)Lc * 384 * 1536 * 2;
    u16* wheadT = (u16*)(ws + off); off += (size_t)128 * 384 * 2;  // padded
    const size_t per_b = (size_t)Tc * (Ec + 1152 + Ec + FFc) * 2;  // 1.77 MB
    if (ws_size < off + per_b) {
        poison_kernel<<<GRD(out_size), 256, 0, stream>>>(out, out_size, 200.0f);
        return;
    }
    int CB = (int)((ws_size - off) / per_b);
    if (CB > Bc) CB = Bc;
    u16* xn_c = (u16*)(ws + off);
    u16* qkv_c = xn_c + (size_t)CB * Tc * Ec;
    u16* o_c = qkv_c + (size_t)CB * Tc * 1152;
    u16* ff_c = o_c + (size_t)CB * Tc * Ec;

    // ---- weight transposes (bf16) -----------------------------------------
    trans_qkv_kernel<<<GRD(Lc * Hc * Ec * 192), 256, 0, stream>>>(wqkv, wqkvT);
    trans_w_kernel<<<GRD(Lc * Ec * Ec), 256, 0, stream>>>(wproj, wprojT, Ec, Ec);
    trans_w_kernel<<<GRD(Lc * Ec * FFc), 256, 0, stream>>>(w1, w1T, Ec, FFc);
    trans_w_kernel<<<GRD(Lc * FFc * Ec), 256, 0, stream>>>(w2, w2T, FFc, Ec);
    hipMemsetAsync(wheadT, 0, (size_t)128 * 384 * 2, stream);
    trans_head_kernel<<<GRD(Ec * Vc), 256, 0, stream>>>(whead, wheadT);

    embed_kernel<<<GRD(Mc * Ec), 256, 0, stream>>>(ctx, tok, pos, x);

    for (int l = 0; l < Lc; ++l) {
        for (int b0 = 0; b0 < Bc; b0 += CB) {
            int bcnt = (Bc - b0 < CB) ? (Bc - b0) : CB;
            int rows = bcnt * Tc;
            float* xc = x + (size_t)b0 * Tc * Ec;
            ln_kernel<<<rows / 4, 256, 0, stream>>>(
                xc, xn_c, ln1g + l * Ec, ln1b + l * Ec, rows);
            mfma_gemm<false, false, true><<<dim3(1152 / 128, rows / 128), 256, 0, stream>>>(
                xn_c, wqkvT + (size_t)l * 1152 * 384, nullptr, nullptr, qkv_c,
                384, 1152, 1152);
            attn_kernel<<<dim3(Tc / 64, Hc, bcnt), 256, 0, stream>>>(qkv_c, o_c);
            mfma_gemm<false, true, false><<<dim3(Ec / 128, rows / 128), 256, 0, stream>>>(
                o_c, wprojT + (size_t)l * 384 * 384, bproj + l * Ec, xc, xc,
                384, Ec, Ec);
            ln_kernel<<<rows / 4, 256, 0, stream>>>(
                xc, xn_c, ln2g + l * Ec, ln2b + l * Ec, rows);
            mfma_gemm<true, false, true><<<dim3(FFc / 128, rows / 128), 256, 0, stream>>>(
                xn_c, w1T + (size_t)l * 1536 * 384, b1 + l * FFc, nullptr, ff_c,
                384, FFc, FFc);
            mfma_gemm<false, true, false><<<dim3(Ec / 128, rows / 128), 256, 0, stream>>>(
                ff_c, w2T + (size_t)l * 384 * 1536, b2 + l * Ec, xc, xc,
                1536, Ec, Ec);
        }
    }
    for (int b0 = 0; b0 < Bc; b0 += CB) {
        int bcnt = (Bc - b0 < CB) ? (Bc - b0) : CB;
        int rows = bcnt * Tc;
        float* xc = x + (size_t)b0 * Tc * Ec;
        ln_kernel<<<rows / 4, 256, 0, stream>>>(xc, xn_c, lnfg, lnfb, rows);
        mfma_gemm<false, false, false><<<dim3(1, rows / 128), 256, 0, stream>>>(
            xn_c, wheadT, bhead, nullptr, out + (size_t)b0 * Tc * Vc,
            384, Vc, Vc);
    }
}